// Round 1
// baseline (6225.224 us; speedup 1.0000x reference)
//
#include <hip/hip_runtime.h>

// RecurrentGaussianActor: fused LSTM(64->256) + Linear+ReLU(256) + 2 heads(16).
// Strategy: one workgroup per batch row (256 WGs x 512 threads), persistent over
// all T=1000 steps. W_hh resident per-CU as f16: K-pairs [0,32) in LDS
// ([pair][row] layout, conflict-free), K-pairs [32,128) in 192 VGPRs/thread.
// Input projection and layer2/heads processed in chunks of 8 steps with weights
// streamed from L2 (amortized). All dots use v_dot2_f32_f16 (fp32 accumulate).

#define NB 256
#define NT 1000
#define NF 64
#define NH 256
#define NG 1024
#define NA 16
#define NTHREADS 512
#define CHUNK 8
#define NCHUNK (NT / CHUNK)
#define LP 32   // h-pairs of W_hh kept in LDS
#define RP 96   // h-pairs of W_hh kept in registers (per row, 2 rows/thread)

typedef _Float16 h2 __attribute__((ext_vector_type(2)));
typedef float f4 __attribute__((ext_vector_type(4)));

__device__ __forceinline__ float fdot2(h2 a, h2 b, float c) {
#if __has_builtin(__builtin_amdgcn_fdot2)
  return __builtin_amdgcn_fdot2(a, b, c, false);
#else
  return c + (float)a[0] * (float)b[0] + (float)a[1] * (float)b[1];
#endif
}

__device__ __forceinline__ float sigmoidf_(float x) {
  return 1.f / (1.f + __expf(-x));
}
__device__ __forceinline__ float tanhfast(float x) {
  float e = __expf(-2.f * fabsf(x));
  float r = (1.f - e) / (1.f + e);
  return x < 0.f ? -r : r;
}

// ---- prep: convert/pack weights to f16 pairs in workspace (~790 KB) ----
__global__ void prep_kernel(const float* __restrict__ Wih, const float* __restrict__ Whh,
                            const float* __restrict__ bih, const float* __restrict__ bhh,
                            const float* __restrict__ W2, const float* __restrict__ Wm,
                            const float* __restrict__ Ws,
                            h2* __restrict__ whh, h2* __restrict__ wih,
                            h2* __restrict__ w2w, h2* __restrict__ wmh,
                            float* __restrict__ bg) {
  int i = blockIdx.x * 256 + threadIdx.x;
  if (i < 1024 * 128) {  // W_hh [1024][256] -> [1024][128] pairs
    int j = i >> 7, p = i & 127;
    whh[i] = h2{(_Float16)Whh[j * 256 + 2 * p], (_Float16)Whh[j * 256 + 2 * p + 1]};
  }
  if (i < 1024 * 32) {   // W_ih [1024][64] -> [1024][32] pairs
    int j = i >> 5, p = i & 31;
    wih[i] = h2{(_Float16)Wih[j * 64 + 2 * p], (_Float16)Wih[j * 64 + 2 * p + 1]};
  }
  if (i < 256 * 128) {   // W2 [256][256] -> [256][128] pairs
    int j = i >> 7, p = i & 127;
    w2w[i] = h2{(_Float16)W2[j * 256 + 2 * p], (_Float16)W2[j * 256 + 2 * p + 1]};
  }
  if (i < 32 * 128) {    // Wm rows 0..15, Ws rows 16..31
    int j = i >> 7, p = i & 127;
    float v0, v1;
    if (j < 16) { v0 = Wm[j * 256 + 2 * p]; v1 = Wm[j * 256 + 2 * p + 1]; }
    else        { v0 = Ws[(j - 16) * 256 + 2 * p]; v1 = Ws[(j - 16) * 256 + 2 * p + 1]; }
    wmh[i] = h2{(_Float16)v0, (_Float16)v1};
  }
  if (i < 1024) bg[i] = bih[i] + bhh[i];
}

// ---- main fused persistent kernel: 1 WG per batch row ----
__global__ __launch_bounds__(NTHREADS, 2) void actor_kernel(
    const float* __restrict__ obs,
    const h2* __restrict__ whh, const h2* __restrict__ wih,
    const h2* __restrict__ w2w, const h2* __restrict__ wmh,
    const float* __restrict__ bg, const float* __restrict__ b2,
    const float* __restrict__ bm, const float* __restrict__ bs,
    float* __restrict__ out) {
  __shared__ h2 whh_l[LP * 1024];        // 131072 B, [pair][row]
  __shared__ _Float16 xg_l[CHUNK * NG];  // 16384 B
  __shared__ float gbuf[NG];             // 4096 B
  __shared__ h2 hbuf[NH / 2];            // 512 B  (current h, f16 pairs)
  __shared__ h2 hch[CHUNK * NH / 2];     // 4096 B (h history for chunk)
  __shared__ h2 xbuf[CHUNK * NF / 2];    // 1024 B (obs chunk, f16 pairs)
  __shared__ h2 x2b[CHUNK * NH / 2];     // 4096 B (layer2 out, f16 pairs)
  // total 161280 B <= 163840 (gfx950 LDS)

  const int tid = threadIdx.x;
  const int b = blockIdx.x;
  const int r0 = tid, r1 = tid + NTHREADS;  // this thread's two gate rows

  // resident W_hh register fragments: pairs [LP, 128) of rows r0, r1
  h2 wa[RP], wb[RP];
  {
    const h2* s0 = whh + r0 * 128 + LP;
    const h2* s1 = whh + r1 * 128 + LP;
#pragma unroll
    for (int p = 0; p < RP; p++) wa[p] = s0[p];
#pragma unroll
    for (int p = 0; p < RP; p++) wb[p] = s1[p];
  }
  // LDS-resident W_hh slice: pairs [0, LP), layout [pair][row]
  for (int k = tid; k < LP * 1024; k += NTHREADS) {
    int row = k >> 5, p = k & 31;
    whh_l[p * 1024 + row] = whh[row * 128 + p];
  }
  if (tid < NH / 2) hbuf[tid] = h2{(_Float16)0.f, (_Float16)0.f};
  float c_state = 0.f;  // thread u<256 owns cell state of unit u
  const float biasg0 = bg[r0], biasg1 = bg[r1];
  const float b2v = b2[tid & 255];
  const int oh = tid & 31;
  const float hbv = (oh < NA) ? bm[oh] : bs[oh - NA];
  __syncthreads();

  const float* obs_b = obs + (size_t)b * NT * NF;
  float* out_means = out;
  float* out_stds = out + (size_t)NB * NT * NA;

  for (int ch = 0; ch < NCHUNK; ++ch) {
    const int t0 = ch * CHUNK;

    // stage obs chunk -> f16 pairs in LDS
    if (tid < 128) {
      int t = tid >> 4, fq = tid & 15;
      f4 v = *(const f4*)(obs_b + (size_t)(t0 + t) * NF + fq * 4);
      xbuf[t * 32 + fq * 2] = h2{(_Float16)v[0], (_Float16)v[1]};
      xbuf[t * 32 + fq * 2 + 1] = h2{(_Float16)v[2], (_Float16)v[3]};
    }
    __syncthreads();

    // xg = obs @ W_ih^T + (b_ih+b_hh) for the chunk (W_ih streamed from L2)
#pragma unroll
    for (int rr = 0; rr < 2; ++rr) {
      const int row = rr ? r1 : r0;
      const float bias = rr ? biasg1 : biasg0;
      float acc[CHUNK];
#pragma unroll
      for (int t = 0; t < CHUNK; t++) acc[t] = bias;
      const h2* wrow = wih + row * 32;
#pragma unroll
      for (int pc = 0; pc < 4; pc++) {
        h2 w8[8];
#pragma unroll
        for (int q = 0; q < 8; q++) w8[q] = wrow[pc * 8 + q];
#pragma unroll
        for (int t = 0; t < CHUNK; t++)
#pragma unroll
          for (int q = 0; q < 8; q++)
            acc[t] = fdot2(xbuf[t * 32 + pc * 8 + q], w8[q], acc[t]);
      }
#pragma unroll
      for (int t = 0; t < CHUNK; t++) xg_l[t * NG + row] = (_Float16)acc[t];
    }
    __syncthreads();

    // 8 recurrent LSTM steps
    for (int t = 0; t < CHUNK; t++) {
      float acc0 = (float)xg_l[t * NG + r0];
      float acc1 = (float)xg_l[t * NG + r1];
#pragma unroll
      for (int p = 0; p < LP; p++) {  // LDS part of W_hh
        h2 hp = hbuf[p];              // broadcast
        acc0 = fdot2(hp, whh_l[p * 1024 + r0], acc0);
        acc1 = fdot2(hp, whh_l[p * 1024 + r1], acc1);
      }
#pragma unroll
      for (int p = 0; p < RP; p++) {  // register part of W_hh
        h2 hp = hbuf[LP + p];         // broadcast
        acc0 = fdot2(hp, wa[p], acc0);
        acc1 = fdot2(hp, wb[p], acc1);
      }
      gbuf[r0] = acc0;
      gbuf[r1] = acc1;
      __syncthreads();
      if (tid < NH) {  // gate order i,f,g,o (rows u, 256+u, 512+u, 768+u)
        float gi = sigmoidf_(gbuf[tid]);
        float gf = sigmoidf_(gbuf[NH + tid]);
        float gg = tanhfast(gbuf[2 * NH + tid]);
        float go = sigmoidf_(gbuf[3 * NH + tid]);
        c_state = gf * c_state + gi * gg;
        float hval = go * tanhfast(c_state);
        _Float16 hh = (_Float16)hval;
        ((_Float16*)hbuf)[tid] = hh;
        ((_Float16*)hch)[t * NH + tid] = hh;
      }
      __syncthreads();
    }

    // layer2: x2 = relu(h @ W2^T + b2), W2 streamed from L2
    {
      const int o = tid & 255;
      const int tb = (tid >> 8) * 4;  // 4 timesteps per thread
      float acc[4] = {b2v, b2v, b2v, b2v};
      const h2* wrow = w2w + o * 128;
#pragma unroll
      for (int pc = 0; pc < 16; pc++) {
        h2 w8[8];
#pragma unroll
        for (int q = 0; q < 8; q++) w8[q] = wrow[pc * 8 + q];
#pragma unroll
        for (int tt = 0; tt < 4; tt++)
#pragma unroll
          for (int q = 0; q < 8; q++)
            acc[tt] = fdot2(hch[(tb + tt) * 128 + pc * 8 + q], w8[q], acc[tt]);
      }
#pragma unroll
      for (int tt = 0; tt < 4; tt++) {
        float v = fmaxf(acc[tt], 0.f);
        ((_Float16*)x2b)[(tb + tt) * NH + o] = (_Float16)v;
      }
    }
    __syncthreads();

    // heads: means + stds (32 outputs x 8 timesteps on first 256 threads)
    if (tid < 256) {
      const int tt = tid >> 5;
      const h2* wrow = wmh + oh * 128;
      float acc = 0.f;
#pragma unroll
      for (int p = 0; p < 128; p++) acc = fdot2(x2b[tt * 128 + p], wrow[p], acc);
      acc += hbv;
      const size_t idx = ((size_t)b * NT + (t0 + tt)) * NA + (oh & 15);
      if (oh < NA) {
        out_means[idx] = acc;
      } else {
        float ls = fminf(fmaxf(acc, -20.f), 2.f);
        out_stds[idx] = __expf(ls);
      }
    }
    // no barrier needed: next write to x2b is after the next chunk's step-loop
    // barriers; xbuf re-stage is followed by a barrier before first use.
  }
}

extern "C" void kernel_launch(void* const* d_in, const int* in_sizes, int n_in,
                              void* d_out, int out_size, void* d_ws, size_t ws_size,
                              hipStream_t stream) {
  const float* obs = (const float*)d_in[0];
  const float* Wih = (const float*)d_in[1];
  const float* Whh = (const float*)d_in[2];
  const float* bih = (const float*)d_in[3];
  const float* bhh = (const float*)d_in[4];
  const float* W2 = (const float*)d_in[5];
  const float* b2 = (const float*)d_in[6];
  const float* Wm = (const float*)d_in[7];
  const float* bm = (const float*)d_in[8];
  const float* Ws = (const float*)d_in[9];
  const float* bs = (const float*)d_in[10];

  // workspace layout (f16-packed weights, ~807 KB)
  char* ws = (char*)d_ws;
  h2* whh = (h2*)(ws + 0);        // 512 KB
  h2* wih = (h2*)(ws + 524288);   // 128 KB
  h2* w2w = (h2*)(ws + 655360);   // 128 KB
  h2* wmh = (h2*)(ws + 786432);   // 16 KB
  float* bg = (float*)(ws + 802816);  // 4 KB

  prep_kernel<<<512, 256, 0, stream>>>(Wih, Whh, bih, bhh, W2, Wm, Ws,
                                       whh, wih, w2w, wmh, bg);
  actor_kernel<<<NB, NTHREADS, 0, stream>>>(obs, whh, wih, w2w, wmh, bg, b2, bm,
                                            bs, (float*)d_out);
}

// Round 2
// 4448.232 us; speedup vs baseline: 1.3995x; 1.3995x over previous
//
#include <hip/hip_runtime.h>

// RecurrentGaussianActor: fused LSTM(64->256) + Linear+ReLU(256) + 2 heads(16).
// One WG per batch row (256 WGs x 512 threads), persistent over T=1000 steps.
// W_hh fully CU-resident in f16: pairs [0,32) in LDS as [p4][row] h8 entries
// (b128 reads), pairs [32,128) in 192 VGPRs/thread loaded VOLATILE so the
// compiler cannot rematerialize them from global inside the step loop (the
// round-1 failure mode: VGPR=128 + 6.3 GB HBM fetch = in-loop reloads).

#define NB 256
#define NT 1000
#define NF 64
#define NH 256
#define NG 1024
#define NA 16
#define NTHREADS 512
#define CHUNK 8
#define NCHUNK (NT / CHUNK)

typedef _Float16 h2 __attribute__((ext_vector_type(2)));
typedef _Float16 h8 __attribute__((ext_vector_type(8)));
typedef float f4 __attribute__((ext_vector_type(4)));

__device__ __forceinline__ float fdot2(h2 a, h2 b, float c) {
  return __builtin_amdgcn_fdot2(a, b, c, false);
}
__device__ __forceinline__ float fexp2(float x) { return __builtin_amdgcn_exp2f(x); }
__device__ __forceinline__ float frcp(float x) { return __builtin_amdgcn_rcpf(x); }
__device__ __forceinline__ float sigmoidf_(float x) {
  return frcp(1.f + fexp2(-1.4426950408889634f * x));
}
__device__ __forceinline__ float tanhfast(float x) {
  float a = fabsf(x);
  float e = fexp2(-2.8853900817779268f * a);
  float r = (1.f - e) * frcp(1.f + e);
  return __builtin_copysignf(r, x);
}
// dot of 8 f16 elements held in two h8 vectors (4 chained v_dot2_f32_f16)
__device__ __forceinline__ float dot8(h8 x, h8 w, float acc) {
  acc = fdot2(__builtin_shufflevector(x, x, 0, 1), __builtin_shufflevector(w, w, 0, 1), acc);
  acc = fdot2(__builtin_shufflevector(x, x, 2, 3), __builtin_shufflevector(w, w, 2, 3), acc);
  acc = fdot2(__builtin_shufflevector(x, x, 4, 5), __builtin_shufflevector(w, w, 4, 5), acc);
  acc = fdot2(__builtin_shufflevector(x, x, 6, 7), __builtin_shufflevector(w, w, 6, 7), acc);
  return acc;
}

// ---- prep: convert/pack weights to f16 pairs in workspace (~790 KB) ----
__global__ void prep_kernel(const float* __restrict__ Wih, const float* __restrict__ Whh,
                            const float* __restrict__ bih, const float* __restrict__ bhh,
                            const float* __restrict__ W2, const float* __restrict__ Wm,
                            const float* __restrict__ Ws,
                            h2* __restrict__ whh, h2* __restrict__ wih,
                            h2* __restrict__ w2w, h2* __restrict__ wmh,
                            float* __restrict__ bg) {
  int i = blockIdx.x * 256 + threadIdx.x;
  if (i < 1024 * 128) {  // W_hh [1024][256] -> [1024][128] pairs
    int j = i >> 7, p = i & 127;
    whh[i] = h2{(_Float16)Whh[j * 256 + 2 * p], (_Float16)Whh[j * 256 + 2 * p + 1]};
  }
  if (i < 1024 * 32) {   // W_ih [1024][64] -> [1024][32] pairs
    int j = i >> 5, p = i & 31;
    wih[i] = h2{(_Float16)Wih[j * 64 + 2 * p], (_Float16)Wih[j * 64 + 2 * p + 1]};
  }
  if (i < 256 * 128) {   // W2 [256][256] -> [256][128] pairs
    int j = i >> 7, p = i & 127;
    w2w[i] = h2{(_Float16)W2[j * 256 + 2 * p], (_Float16)W2[j * 256 + 2 * p + 1]};
  }
  if (i < 32 * 128) {    // Wm rows 0..15, Ws rows 16..31
    int j = i >> 7, p = i & 127;
    float v0, v1;
    if (j < 16) { v0 = Wm[j * 256 + 2 * p]; v1 = Wm[j * 256 + 2 * p + 1]; }
    else        { v0 = Ws[(j - 16) * 256 + 2 * p]; v1 = Ws[(j - 16) * 256 + 2 * p + 1]; }
    wmh[i] = h2{(_Float16)v0, (_Float16)v1};
  }
  if (i < 1024) bg[i] = bih[i] + bhh[i];
}

// ---- main fused persistent kernel: 1 WG per batch row ----
__global__ __launch_bounds__(NTHREADS, 2) void actor_kernel(
    const float* __restrict__ obs,
    const h2* __restrict__ whh, const h2* __restrict__ wih,
    const h2* __restrict__ w2w, const h2* __restrict__ wmh,
    const float* __restrict__ bg, const float* __restrict__ b2,
    const float* __restrict__ bm, const float* __restrict__ bs,
    float* __restrict__ out) {
  __shared__ __align__(16) h8 whh_l[8 * 1024];     // 131072 B, [p4][row], pairs 0..31
  __shared__ __align__(16) _Float16 xg_l[CHUNK * NG];  // 16384 B
  __shared__ __align__(16) float gbuf[NG];             // 4096 B
  __shared__ __align__(16) h2 hbuf[NH / 2];            // 512 B   current h
  __shared__ __align__(16) h2 hch[CHUNK * NH / 2];     // 4096 B  h history
  __shared__ __align__(16) h2 xbuf[CHUNK * NF / 2];    // 1024 B  obs chunk
  __shared__ __align__(16) h2 x2b[CHUNK * NH / 2];     // 4096 B  layer2 out
  // total 161280 B <= 163840

  const int tid = threadIdx.x;
  const int b = blockIdx.x;
  const int r0 = tid, r1 = tid + NTHREADS;  // this thread's two gate rows

  // ---- register-resident W_hh pairs [32,128): VOLATILE loads (no remat) ----
  h8 wa8[24], wb8[24];  // 96+96 VGPRs
  {
    const volatile h8* vw = (const volatile h8*)whh;  // row stride = 32 h8
#pragma unroll
    for (int j = 0; j < 24; j++) wa8[j] = vw[r0 * 32 + 8 + j];
#pragma unroll
    for (int j = 0; j < 24; j++) wb8[j] = vw[r1 * 32 + 8 + j];
  }
  // ---- LDS-resident W_hh pairs [0,32): layout [p4][row] h8 ----
  {
    const h8* whh8 = (const h8*)whh;
    for (int k = tid; k < 8 * 1024; k += NTHREADS) {
      int p4 = k >> 10, row = k & 1023;
      whh_l[p4 * 1024 + row] = whh8[row * 32 + p4];
    }
  }
  if (tid < NH / 2) hbuf[tid] = h2{(_Float16)0.f, (_Float16)0.f};
  float c_state = 0.f;  // thread u<256 owns cell state of unit u
  const float biasg0 = bg[r0], biasg1 = bg[r1];
  const float b2v = b2[tid & 255];
  const int oh = tid & 31;
  const float hbv = (oh < NA) ? bm[oh] : bs[oh - NA];
  __syncthreads();

  const float* obs_b = obs + (size_t)b * NT * NF;
  float* out_means = out;
  float* out_stds = out + (size_t)NB * NT * NA;

  for (int ch = 0; ch < NCHUNK; ++ch) {
    const int t0 = ch * CHUNK;

    // ---- stage obs chunk -> f16 pairs in LDS ----
    if (tid < 128) {
      int t = tid >> 4, fq = tid & 15;
      f4 v = *(const f4*)(obs_b + (size_t)(t0 + t) * NF + fq * 4);
      xbuf[t * 32 + fq * 2] = h2{(_Float16)v[0], (_Float16)v[1]};
      xbuf[t * 32 + fq * 2 + 1] = h2{(_Float16)v[2], (_Float16)v[3]};
    }
    __syncthreads();

    // ---- xg = obs @ W_ih^T + (b_ih+b_hh) for the chunk ----
#pragma unroll
    for (int rr = 0; rr < 2; ++rr) {
      const int row = rr ? r1 : r0;
      const float bias = rr ? biasg1 : biasg0;
      float acc[CHUNK];
#pragma unroll
      for (int t = 0; t < CHUNK; t++) acc[t] = bias;
      const h8* wrow = (const h8*)wih + row * 8;
#pragma unroll
      for (int jh = 0; jh < 2; jh++) {
        h8 w[4];
#pragma unroll
        for (int q = 0; q < 4; q++) w[q] = wrow[jh * 4 + q];
#pragma unroll
        for (int t = 0; t < CHUNK; t++) {
#pragma unroll
          for (int q = 0; q < 4; q++) {
            h8 xv = *(const h8*)&xbuf[t * 32 + jh * 16 + q * 4];
            acc[t] = dot8(xv, w[q], acc[t]);
          }
        }
      }
#pragma unroll
      for (int t = 0; t < CHUNK; t++) xg_l[t * NG + row] = (_Float16)acc[t];
    }
    __syncthreads();

    // ---- 8 recurrent LSTM steps ----
    for (int t = 0; t < CHUNK; t++) {
      float a0a = (float)xg_l[t * NG + r0], a0b = 0.f;
      float a1a = (float)xg_l[t * NG + r1], a1b = 0.f;
      // LDS part: pairs [0,32)
#pragma unroll
      for (int p4 = 0; p4 < 8; p4++) {
        h8 hv = *(const h8*)&hbuf[p4 * 4];  // broadcast b128
        h8 w0 = whh_l[p4 * 1024 + r0];
        h8 w1 = whh_l[p4 * 1024 + r1];
        if (p4 & 1) { a0b = dot8(hv, w0, a0b); a1b = dot8(hv, w1, a1b); }
        else        { a0a = dot8(hv, w0, a0a); a1a = dot8(hv, w1, a1a); }
      }
      // register part: pairs [32,128)
#pragma unroll
      for (int j = 0; j < 24; j++) {
        h8 hv = *(const h8*)&hbuf[32 + 4 * j];  // broadcast b128
        if (j & 1) { a0b = dot8(hv, wa8[j], a0b); a1b = dot8(hv, wb8[j], a1b); }
        else       { a0a = dot8(hv, wa8[j], a0a); a1a = dot8(hv, wb8[j], a1a); }
      }
      gbuf[r0] = a0a + a0b;
      gbuf[r1] = a1a + a1b;
      __syncthreads();
      if (tid < NH) {  // gate rows: i=u, f=256+u, g=512+u, o=768+u
        float gi = sigmoidf_(gbuf[tid]);
        float gf = sigmoidf_(gbuf[NH + tid]);
        float gg = tanhfast(gbuf[2 * NH + tid]);
        float go = sigmoidf_(gbuf[3 * NH + tid]);
        c_state = gf * c_state + gi * gg;
        float hval = go * tanhfast(c_state);
        _Float16 hh = (_Float16)hval;
        ((_Float16*)hbuf)[tid] = hh;
        ((_Float16*)hch)[t * NH + tid] = hh;
      }
      __syncthreads();
    }

    // ---- layer2: x2 = relu(h @ W2^T + b2) ----
    {
      const int o = tid & 255;
      const int tb = (tid >> 8) * 4;  // 4 timesteps per thread
      float acc[4] = {b2v, b2v, b2v, b2v};
      const h8* wrow = (const h8*)w2w + o * 32;
#pragma unroll 2
      for (int c = 0; c < 8; c++) {
        h8 w[4];
#pragma unroll
        for (int q = 0; q < 4; q++) w[q] = wrow[c * 4 + q];
#pragma unroll
        for (int tt = 0; tt < 4; tt++) {
#pragma unroll
          for (int q = 0; q < 4; q++) {
            h8 xv = *(const h8*)&hch[(tb + tt) * 128 + c * 16 + q * 4];
            acc[tt] = dot8(xv, w[q], acc[tt]);
          }
        }
      }
#pragma unroll
      for (int tt = 0; tt < 4; tt++)
        ((_Float16*)x2b)[(tb + tt) * NH + o] = (_Float16)fmaxf(acc[tt], 0.f);
    }
    __syncthreads();

    // ---- heads: 32 outputs x 8 timesteps on first 256 threads ----
    if (tid < 256) {
      const int tt = tid >> 5;
      const h8* wrow = (const h8*)wmh + oh * 32;
      float acc = 0.f;
#pragma unroll 4
      for (int c = 0; c < 32; c++) {
        h8 xv = *(const h8*)&x2b[tt * 128 + c * 4];
        acc = dot8(xv, wrow[c], acc);
      }
      acc += hbv;
      const size_t idx = ((size_t)b * NT + (t0 + tt)) * NA + (oh & 15);
      if (oh < NA) {
        out_means[idx] = acc;
      } else {
        float ls = fminf(fmaxf(acc, -20.f), 2.f);
        out_stds[idx] = fexp2(1.4426950408889634f * ls);
      }
    }
    // no trailing barrier needed: next writes to x2b/xbuf are separated from
    // these reads by the next chunk's staging/step barriers.
  }
}

extern "C" void kernel_launch(void* const* d_in, const int* in_sizes, int n_in,
                              void* d_out, int out_size, void* d_ws, size_t ws_size,
                              hipStream_t stream) {
  const float* obs = (const float*)d_in[0];
  const float* Wih = (const float*)d_in[1];
  const float* Whh = (const float*)d_in[2];
  const float* bih = (const float*)d_in[3];
  const float* bhh = (const float*)d_in[4];
  const float* W2 = (const float*)d_in[5];
  const float* b2 = (const float*)d_in[6];
  const float* Wm = (const float*)d_in[7];
  const float* bm = (const float*)d_in[8];
  const float* Ws = (const float*)d_in[9];
  const float* bs = (const float*)d_in[10];

  char* ws = (char*)d_ws;
  h2* whh = (h2*)(ws + 0);            // 512 KB
  h2* wih = (h2*)(ws + 524288);       // 128 KB
  h2* w2w = (h2*)(ws + 655360);       // 128 KB
  h2* wmh = (h2*)(ws + 786432);       // 16 KB
  float* bg = (float*)(ws + 802816);  // 4 KB

  prep_kernel<<<512, 256, 0, stream>>>(Wih, Whh, bih, bhh, W2, Wm, Ws,
                                       whh, wih, w2w, wmh, bg);
  actor_kernel<<<NB, NTHREADS, 0, stream>>>(obs, whh, wih, w2w, wmh, bg, b2, bm,
                                            bs, (float*)d_out);
}